// Round 1
// baseline (97.071 us; speedup 1.0000x reference)
//
#include <hip/hip_runtime.h>

#define NB 1000000
#define N_IN 59
#define N_VALUES 12
#define BLOCK 256

__global__ __launch_bounds__(BLOCK) void value_model_kernel(
    const float* __restrict__ act,    // [B, 59]
    const int*   __restrict__ cards,  // [B, 4, 3] int32
    const float* __restrict__ W,      // [12, 59]
    const float* __restrict__ bias,   // [12]
    float* __restrict__ out,          // [B, 4]
    int B)
{
    __shared__ float Wt[N_IN][N_VALUES];   // transposed W: Wt[j][v]
    __shared__ float fv[N_VALUES][BLOCK];  // per-thread feature values

    const int tid = threadIdx.x;

    // Cooperative load of W into LDS, transposed. W is [12][59] row-major.
    for (int i = tid; i < N_IN * N_VALUES; i += BLOCK) {
        int v = i / N_IN;
        int j = i - v * N_IN;
        Wt[j][v] = W[i];
    }
    __syncthreads();

    const int row = blockIdx.x * BLOCK + tid;
    if (row < B) {
        float acc[N_VALUES];
        #pragma unroll
        for (int v = 0; v < N_VALUES; ++v) acc[v] = bias[v];

        const float* a = act + (long)row * N_IN;
        #pragma unroll
        for (int j = 0; j < N_IN; ++j) {
            float x = a[j];
            #pragma unroll
            for (int v = 0; v < N_VALUES; ++v)
                acc[v] = fmaf(x, Wt[j][v], acc[v]);
        }

        // Stage feature values in LDS so the gather can use runtime indices
        // without spilling registers to scratch. fv[v][tid]: bank = tid%32,
        // conflict-free for any v.
        #pragma unroll
        for (int v = 0; v < N_VALUES; ++v) fv[v][tid] = acc[v];
        // each thread reads only its own column -> no barrier needed

        const int4* cp = (const int4*)(cards + (long)row * 12);
        int4 c0 = cp[0];
        int4 c1 = cp[1];
        int4 c2 = cp[2];

        float4 o;
        o.x = fv[c0.x][tid] + fv[c0.y][tid] + fv[c0.z][tid];
        o.y = fv[c0.w][tid] + fv[c1.x][tid] + fv[c1.y][tid];
        o.z = fv[c1.z][tid] + fv[c1.w][tid] + fv[c2.x][tid];
        o.w = fv[c2.y][tid] + fv[c2.z][tid] + fv[c2.w][tid];

        *(float4*)(out + (long)row * 4) = o;
    }
}

extern "C" void kernel_launch(void* const* d_in, const int* in_sizes, int n_in,
                              void* d_out, int out_size, void* d_ws, size_t ws_size,
                              hipStream_t stream) {
    const float* act   = (const float*)d_in[0];
    const int*   cards = (const int*)d_in[1];
    const float* W     = (const float*)d_in[2];
    const float* bias  = (const float*)d_in[3];
    float* out = (float*)d_out;

    const int B = in_sizes[0] / N_IN;  // 1,000,000
    const int grid = (B + BLOCK - 1) / BLOCK;
    value_model_kernel<<<grid, BLOCK, 0, stream>>>(act, cards, W, bias, out, B);
}